// Round 12
// baseline (553.334 us; speedup 1.0000x reference)
//
#include <hip/hip_runtime.h>
#include <cmath>

// x [B=4096][T=512][D=4], H=32, gates 4H=128 (PyTorch order i,f,g,o).
constexpr int T   = 512;
constexpr int D   = 4;
constexpr int H   = 32;
constexpr int BT  = 16;    // batch cols per block — ALL real
constexpr int BLK = 512;   // 8 waves: (layer, unit-half, act-sub)

typedef short bf8 __attribute__((ext_vector_type(8)));  // 8 bf16 (4 VGPRs)
typedef short s2v __attribute__((ext_vector_type(2)));  // 2 bf16 (4B)
typedef float f4  __attribute__((ext_vector_type(4)));  // MFMA C/D
typedef float f2  __attribute__((ext_vector_type(2)));

static __device__ __forceinline__ float sigm(float z) {
    return __builtin_amdgcn_rcpf(1.0f + __expf(-z));
}
static __device__ __forceinline__ float tanh_f(float z) {
    return fmaf(__builtin_amdgcn_rcpf(1.0f + __expf(-2.0f * z)), 2.0f, -1.0f);
}
// fp32 -> bf16 hi (truncate) + bf16 lo (residual): hi+lo ~ 16 mantissa bits
static __device__ __forceinline__ void splitf(float v, short& hi, short& lo) {
    unsigned uv = __float_as_uint(v);
    hi = (short)(uv >> 16);
    float r = v - __uint_as_float(uv & 0xffff0000u);
    lo = (short)(__float_as_uint(r) >> 16);
}

// R11 structure (lane-local i,f,g,o in C/D regs, no gate LDS, 1 barrier,
// all-real BT=16) + activation-duplication: wave pair (sub=0/1) computes
// IDENTICAL 24 MFMAs for (layer, ug), then splits the state update —
// sub=0 owns quad-rows r={0,1}, sub=1 owns r={2,3}. MFMA cost doubles
// (still hidden on the matrix pipe); per-wave VALU (the binding resource
// at R11's 1 wave/SIMD) nearly halves, and 2 waves/SIMD fill each other's
// ds_read/exp/MFMA latency. Grid 256 x 512 = 1 block/CU, 8 waves.
__global__ __launch_bounds__(BLK, 2) void lstm_dup(
    const float* __restrict__ x,
    const float* __restrict__ W_ih0, const float* __restrict__ W_hh0,
    const float* __restrict__ b_ih0, const float* __restrict__ b_hh0,
    const float* __restrict__ W_ih1, const float* __restrict__ W_hh1,
    const float* __restrict__ b_ih1, const float* __restrict__ b_hh1,
    const float* __restrict__ W_out, const float* __restrict__ b_out,
    float* __restrict__ out)
{
    // [buf][col][unit], row stride 56 shorts = 112 B (b128-aligned frags,
    // 2-way bank spread = free)
    __shared__ __align__(16) short h0hi[2][16][56];
    __shared__ __align__(16) short h0lo[2][16][56];
    __shared__ __align__(16) short h1hi[2][16][56];
    __shared__ __align__(16) short h1lo[2][16][56];
    __shared__ __align__(16) float h1f[16][36];     // final h1 fp32 for the head

    const int tid   = threadIdx.x;
    const int w     = tid >> 6;
    const int lane  = tid & 63;
    const int q     = lane >> 4;        // quad
    const int nl    = lane & 15;        // batch col (all real)
    const int layer = w >> 2;           // 0: L1, 1: L2
    const int ug    = ((w >> 1) & 1) << 4;  // unit group offset 0 / 16
    const int sub   = w & 1;            // activation split: rows 2sub, 2sub+1
    const int b0    = blockIdx.x * BT;

    // zero both h buffers
    for (int idx = tid; idx < 2 * 16 * 56; idx += BLK) {
        (&h0hi[0][0][0])[idx] = 0; (&h0lo[0][0][0])[idx] = 0;
        (&h1hi[0][0][0])[idx] = 0; (&h1lo[0][0][0])[idx] = 0;
    }

    // ---- weights: tile g = gate type. A-frag row = 32g + ug + nl, k = 8q+j.
    // W1 dotted with h0 (L1: W_hh0, L2: W_ih1); W2 with the 2nd operand
    // (L1: W_ih0 vs x, K-padded; L2: W_hh1 vs h1). Both sub-waves identical.
    const float* W1 = layer ? W_ih1 : W_hh0;
    bf8 w1h[4], w1l[4], w2h[4], w2l[4];
    f4  bias[4];
    #pragma unroll
    for (int g = 0; g < 4; ++g) {
        const int row = 32 * g + ug + nl;
        #pragma unroll
        for (int j = 0; j < 8; ++j) {
            short a, b;
            splitf(W1[row * H + 8 * q + j], a, b); w1h[g][j] = a; w1l[g][j] = b;
            float v2 = layer ? W_hh1[row * H + 8 * q + j]
                             : ((q == 0 && j < 4) ? W_ih0[row * D + j] : 0.0f);
            splitf(v2, a, b); w2h[g][j] = a; w2l[g][j] = b;
        }
        #pragma unroll
        for (int r = 0; r < 4; ++r) {
            const int gr = 32 * g + ug + 4 * q + r;
            bias[g][r] = layer ? (b_ih1[gr] + b_hh1[gr]) : (b_ih0[gr] + b_hh0[gr]);
        }
    }

    const float4* xp = (const float4*)(x + (size_t)(b0 + nl) * (T * D));
    float4 xcur;
    if (layer == 0) xcur = xp[0];

    float c[2] = {0.0f, 0.0f};   // cell state of the 2 owned units (r = 2sub+{0,1})

    __syncthreads();

    #pragma unroll 1
    for (int i = 0; i <= T; ++i) {
        const int rb = i & 1, wb = rb ^ 1;

        // B-fragments
        bf8 b1h = *(const bf8*)&h0hi[rb][nl][8 * q];   // h0(i-1)
        bf8 b1l = *(const bf8*)&h0lo[rb][nl][8 * q];
        bf8 b2h, b2l;
        if (layer == 0) {   // x(i): k<4 = x, rest zero (A cols k>=4 zero too)
            bf8 z = {0,0,0,0,0,0,0,0};
            b2h = z; b2l = z;
            short a, b;
            splitf(xcur.x, a, b); b2h[0] = a; b2l[0] = b;
            splitf(xcur.y, a, b); b2h[1] = a; b2l[1] = b;
            splitf(xcur.z, a, b); b2h[2] = a; b2l[2] = b;
            splitf(xcur.w, a, b); b2h[3] = a; b2l[3] = b;
            xcur = xp[(i + 1 < T) ? (i + 1) : (T - 1)];   // prefetch
        } else {            // h1(i-2)
            b2h = *(const bf8*)&h1hi[rb][nl][8 * q];
            b2l = *(const bf8*)&h1lo[rb][nl][8 * q];
        }

        // ---- 24 MFMAs (duplicated across the sub pair) ----
        f4 acc[4];
        #pragma unroll
        for (int g = 0; g < 4; ++g) {
            f4 A = bias[g];
            A = __builtin_amdgcn_mfma_f32_16x16x32_bf16(w1h[g], b1h, A, 0, 0, 0);
            A = __builtin_amdgcn_mfma_f32_16x16x32_bf16(w1h[g], b1l, A, 0, 0, 0);
            A = __builtin_amdgcn_mfma_f32_16x16x32_bf16(w1l[g], b1h, A, 0, 0, 0);
            f4 R = {0.0f, 0.0f, 0.0f, 0.0f};
            R = __builtin_amdgcn_mfma_f32_16x16x32_bf16(w2h[g], b2h, R, 0, 0, 0);
            R = __builtin_amdgcn_mfma_f32_16x16x32_bf16(w2h[g], b2l, R, 0, 0, 0);
            R = __builtin_amdgcn_mfma_f32_16x16x32_bf16(w2l[g], b2h, R, 0, 0, 0);
            acc[g] = A + R;
        }

        // ---- state update: 2 units/lane (rows 2sub, 2sub+1 of the quad) ----
        const bool act = layer ? (i >= 1) : (i < T);
        if (act) {
            s2v hh, hl;
            float hv[2];
            #pragma unroll
            for (int r = 0; r < 2; ++r) {
                const int rr = 2 * sub + r;
                float iv = sigm(acc[0][rr]);
                float fv = sigm(acc[1][rr]);
                float gv = tanh_f(acc[2][rr]);
                float ov = sigm(acc[3][rr]);
                c[r] = fmaf(fv, c[r], iv * gv);
                hv[r] = ov * tanh_f(c[r]);
                short a, b; splitf(hv[r], a, b); hh[r] = a; hl[r] = b;
            }
            const int uo = ug + 4 * q + 2 * sub;
            if (layer == 0) {
                *(s2v*)&h0hi[wb][nl][uo] = hh;
                *(s2v*)&h0lo[wb][nl][uo] = hl;
            } else {
                *(s2v*)&h1hi[wb][nl][uo] = hh;
                *(s2v*)&h1lo[wb][nl][uo] = hl;
                if (i == T) {   // h1(T-1) for the output head
                    f2 hw; hw.x = hv[0]; hw.y = hv[1];
                    *(f2*)&h1f[nl][uo] = hw;
                }
            }
        }
        __syncthreads();   // single barrier: buffer wb becomes rb of iter i+1
    }

    // ---- output head: out[b0+n] = b_out + W_out . h1(T-1) ----
    if (tid < BT) {
        float acc = b_out[0];
        #pragma unroll
        for (int u = 0; u < H; ++u) acc = fmaf(W_out[u], h1f[tid][u], acc);
        out[b0 + tid] = acc;
    }
}

extern "C" void kernel_launch(void* const* d_in, const int* in_sizes, int n_in,
                              void* d_out, int out_size, void* d_ws, size_t ws_size,
                              hipStream_t stream) {
    const float* x     = (const float*)d_in[0];
    const float* W_ih0 = (const float*)d_in[1];
    const float* W_hh0 = (const float*)d_in[2];
    const float* b_ih0 = (const float*)d_in[3];
    const float* b_hh0 = (const float*)d_in[4];
    const float* W_ih1 = (const float*)d_in[5];
    const float* W_hh1 = (const float*)d_in[6];
    const float* b_ih1 = (const float*)d_in[7];
    const float* b_hh1 = (const float*)d_in[8];
    const float* W_out = (const float*)d_in[9];
    const float* b_out = (const float*)d_in[10];
    float* out = (float*)d_out;

    const int B = out_size;          // 4096
    lstm_dup<<<B / BT, BLK, 0, stream>>>(x, W_ih0, W_hh0, b_ih0, b_hh0,
                                         W_ih1, W_hh1, b_ih1, b_hh1,
                                         W_out, b_out, out);
}

// Round 13
// 334.748 us; speedup vs baseline: 1.6530x; 1.6530x over previous
//
#include <hip/hip_runtime.h>
#include <cmath>

// x [B=4096][T=512][D=4], H=32, gates 4H=128 (PyTorch order i,f,g,o).
constexpr int T   = 512;
constexpr int D   = 4;
constexpr int H   = 32;
constexpr int BT  = 16;    // batch cols per block — ALL real
constexpr int BLK = 256;   // 4 waves: (layer, unit-half)

constexpr float LOG2E     = 1.44269504088896340736f;
constexpr float NEG2LOG2E = -2.88539008177792681472f;

typedef short bf8 __attribute__((ext_vector_type(8)));  // 8 bf16 (4 VGPRs)
typedef short s4v __attribute__((ext_vector_type(4)));  // 4 bf16 (8B)
typedef float f4  __attribute__((ext_vector_type(4)));  // MFMA C/D

// fp32 -> bf16 round-to-nearest-even (values are finite, well-scaled)
static __device__ __forceinline__ short bf16_rtn(float v) {
    unsigned u = __float_as_uint(v);
    u += 0x7FFFu + ((u >> 16) & 1u);
    return (short)(u >> 16);
}
// sigmoid in exp2 domain: a = -log2e * z  ->  sigma(z) = 1/(1+2^a)
static __device__ __forceinline__ float sigm2(float a) {
    return __builtin_amdgcn_rcpf(1.0f + __builtin_amdgcn_exp2f(a));
}

// R11 topology (best: 450us) with the precision machinery stripped:
// - single-product bf16-RTN MFMAs: 2 per gate (was 6) -> 8 MFMAs/wave
// - h stored as plain bf16 (no hi/lo split): half the h-LDS traffic,
//   no splitf on the store path; c stays fp32 in registers
// - exp2-folded weights: rows pre-scaled by -log2e (i,f,o) / -2log2e (g)
//   so activations use v_exp directly with no preceding v_mul
// Wave w = (layer=w>>1, ug=(w&1)*16) owns all 4 gate tiles for its 16
// units; i,f,g,o of unit ug+4q+r land in the same lane's C/D regs ->
// lane-local state update, ONE barrier/iter, double-buffered h.
__global__ __launch_bounds__(BLK, 1) void lstm_bf16(
    const float* __restrict__ x,
    const float* __restrict__ W_ih0, const float* __restrict__ W_hh0,
    const float* __restrict__ b_ih0, const float* __restrict__ b_hh0,
    const float* __restrict__ W_ih1, const float* __restrict__ W_hh1,
    const float* __restrict__ b_ih1, const float* __restrict__ b_hh1,
    const float* __restrict__ W_out, const float* __restrict__ b_out,
    float* __restrict__ out)
{
    // [buf][col][unit], row stride 56 shorts = 112 B (b128-aligned frags,
    // 2-way bank spread = free)
    __shared__ __align__(16) short h0b[2][16][56];
    __shared__ __align__(16) short h1b[2][16][56];
    __shared__ __align__(16) float h1f[16][36];     // final h1 fp32 for the head

    const int tid   = threadIdx.x;
    const int w     = tid >> 6;
    const int lane  = tid & 63;
    const int q     = lane >> 4;       // quad
    const int nl    = lane & 15;       // batch col (all real)
    const int layer = w >> 1;          // 0: L1, 1: L2
    const int ug    = (w & 1) << 4;    // unit group offset 0 / 16
    const int b0    = blockIdx.x * BT;

    // zero both h buffers
    for (int idx = tid; idx < 2 * 16 * 56; idx += BLK) {
        (&h0b[0][0][0])[idx] = 0;
        (&h1b[0][0][0])[idx] = 0;
    }

    // ---- weights: tile g = gate type. A-frag row = 32g + ug + nl, k = 8q+j.
    // W1 dotted with h0 (L1: W_hh0, L2: W_ih1); W2 with the 2nd operand
    // (L1: W_ih0 vs x, K-padded; L2: W_hh1 vs h1). Rows pre-scaled for exp2.
    const float* W1 = layer ? W_ih1 : W_hh0;
    bf8 w1[4], w2[4];
    f4  bias[4];
    #pragma unroll
    for (int g = 0; g < 4; ++g) {
        const float sc = (g == 2) ? NEG2LOG2E : -LOG2E;
        const int row = 32 * g + ug + nl;
        #pragma unroll
        for (int j = 0; j < 8; ++j) {
            w1[g][j] = bf16_rtn(W1[row * H + 8 * q + j] * sc);
            float v2 = layer ? W_hh1[row * H + 8 * q + j]
                             : ((q == 0 && j < 4) ? W_ih0[row * D + j] : 0.0f);
            w2[g][j] = bf16_rtn(v2 * sc);
        }
        #pragma unroll
        for (int r = 0; r < 4; ++r) {
            const int gr = 32 * g + ug + 4 * q + r;
            bias[g][r] = sc * (layer ? (b_ih1[gr] + b_hh1[gr])
                                     : (b_ih0[gr] + b_hh0[gr]));
        }
    }

    const float4* xp = (const float4*)(x + (size_t)(b0 + nl) * (T * D));
    float4 xcur;
    if (layer == 0) xcur = xp[0];

    float c[4] = {0.0f, 0.0f, 0.0f, 0.0f};   // cell state, fp32, lane-local

    __syncthreads();

    #pragma unroll 1
    for (int i = 0; i <= T; ++i) {
        const int rb = i & 1, wb = rb ^ 1;

        // second-operand fragment first (x is ready pre-barrier for L1;
        // h1 read issued before h0 for L2 so its latency hides under MFMA 1)
        bf8 b2;
        if (layer == 0) {   // x(i): k<4 = x (A cols k>=4 are zero)
            bf8 z = {0,0,0,0,0,0,0,0};
            b2 = z;
            b2[0] = bf16_rtn(xcur.x);
            b2[1] = bf16_rtn(xcur.y);
            b2[2] = bf16_rtn(xcur.z);
            b2[3] = bf16_rtn(xcur.w);
            xcur = xp[(i + 1 < T) ? (i + 1) : (T - 1)];   // prefetch
        } else {            // h1(i-2)
            b2 = *(const bf8*)&h1b[rb][nl][8 * q];
        }
        bf8 b1 = *(const bf8*)&h0b[rb][nl][8 * q];        // h0(i-1)

        // ---- 8 MFMAs: 4 gate tiles x 2-chain (C starts at scaled bias) ----
        f4 acc[4];
        #pragma unroll
        for (int g = 0; g < 4; ++g) {
            f4 A = __builtin_amdgcn_mfma_f32_16x16x32_bf16(w2[g], b2, bias[g], 0, 0, 0);
            A    = __builtin_amdgcn_mfma_f32_16x16x32_bf16(w1[g], b1, A,       0, 0, 0);
            acc[g] = A;
        }

        // ---- lane-local state update: units ug+4q+r, col nl ----
        // acc = -log2e*z (i,f,o) / -2log2e*z (g) -> native exp2 activations
        const bool act = layer ? (i >= 1) : (i < T);
        if (act) {
            s4v hh;
            float hv[4];
            #pragma unroll
            for (int r = 0; r < 4; ++r) {
                float iv = sigm2(acc[0][r]);
                float fv = sigm2(acc[1][r]);
                float gv = fmaf(sigm2(acc[2][r]), 2.0f, -1.0f);
                float ov = sigm2(acc[3][r]);
                c[r] = fmaf(fv, c[r], iv * gv);
                float th = fmaf(sigm2(c[r] * NEG2LOG2E), 2.0f, -1.0f);
                hv[r] = ov * th;
                hh[r] = bf16_rtn(hv[r]);
            }
            if (layer == 0) {
                *(s4v*)&h0b[wb][nl][ug + 4 * q] = hh;
            } else {
                *(s4v*)&h1b[wb][nl][ug + 4 * q] = hh;
                if (i == T) {   // h1(T-1), full fp32, for the output head
                    float4 hw; hw.x = hv[0]; hw.y = hv[1]; hw.z = hv[2]; hw.w = hv[3];
                    *(float4*)&h1f[nl][ug + 4 * q] = hw;
                }
            }
        }
        __syncthreads();   // single barrier: buffer wb becomes rb of iter i+1
    }

    // ---- output head: out[b0+n] = b_out + W_out . h1(T-1) ----
    if (tid < BT) {
        float acc = b_out[0];
        #pragma unroll
        for (int u = 0; u < H; ++u) acc = fmaf(W_out[u], h1f[tid][u], acc);
        out[b0 + tid] = acc;
    }
}

extern "C" void kernel_launch(void* const* d_in, const int* in_sizes, int n_in,
                              void* d_out, int out_size, void* d_ws, size_t ws_size,
                              hipStream_t stream) {
    const float* x     = (const float*)d_in[0];
    const float* W_ih0 = (const float*)d_in[1];
    const float* W_hh0 = (const float*)d_in[2];
    const float* b_ih0 = (const float*)d_in[3];
    const float* b_hh0 = (const float*)d_in[4];
    const float* W_ih1 = (const float*)d_in[5];
    const float* W_hh1 = (const float*)d_in[6];
    const float* b_ih1 = (const float*)d_in[7];
    const float* b_hh1 = (const float*)d_in[8];
    const float* W_out = (const float*)d_in[9];
    const float* b_out = (const float*)d_in[10];
    float* out = (float*)d_out;

    const int B = out_size;          // 4096
    lstm_bf16<<<B / BT, BLK, 0, stream>>>(x, W_ih0, W_hh0, b_ih0, b_hh0,
                                          W_ih1, W_hh1, b_ih1, b_hh1,
                                          W_out, b_out, out);
}